// Round 2
// baseline (253.042 us; speedup 1.0000x reference)
//
#include <hip/hip_runtime.h>

// Problem constants (B=8, T=2048, C=1024, H=64)
#define TB 2048
#define NB 8
#define CEMB 1024
#define HD 64
#define BT (NB*TB)
#define SCALE 0.03125f   // 1/sqrt(1024) — reference scales by n_embd

typedef __attribute__((ext_vector_type(8))) short bf16x8;
typedef __attribute__((ext_vector_type(4))) float f32x4;

__device__ inline short f2bf(float f) {
    union { float f; unsigned u; } v; v.f = f;
    unsigned r = v.u + 0x7fffu + ((v.u >> 16) & 1u);   // RNE
    return (short)(r >> 16);
}

// ---------- K1: pack [Wk;Wq;Wv] into MFMA B-frag order, bf16 ----------
// chunk c: lane=c&63, ntk=c>>6, nt=ntk%12, kc=ntk/12
// W2[((kc*12+nt)*64+lane)*8 + j] = W[n=nt*16+(lane&15)][kc*32+(lane>>4)*8+j]
__global__ __launch_bounds__(256) void wpack(const float* __restrict__ Wk,
                                             const float* __restrict__ Wq,
                                             const float* __restrict__ Wv,
                                             short* __restrict__ W2) {
    int c = blockIdx.x * 256 + threadIdx.x;          // 96 blocks -> 24576 chunks
    int lane = c & 63, ntk = c >> 6;
    int nt = ntk % 12, kc = ntk / 12;
    int n = nt * 16 + (lane & 15);
    int col = kc * 32 + (lane >> 4) * 8;
    const float* src = (n < 64) ? Wk + n * 1024
                     : (n < 128) ? Wq + (n - 64) * 1024
                                 : Wv + (n - 128) * 1024;
    float4 a = *(const float4*)(src + col);
    float4 b = *(const float4*)(src + col + 4);
    bf16x8 o;
    o[0] = f2bf(a.x); o[1] = f2bf(a.y); o[2] = f2bf(a.z); o[3] = f2bf(a.w);
    o[4] = f2bf(b.x); o[5] = f2bf(b.y); o[6] = f2bf(b.z); o[7] = f2bf(b.w);
    *(bf16x8*)(W2 + (size_t)c * 8) = o;
}

// ---------- K2: QKV projection, one independent wave per 16 rows ----------
// No LDS, no barriers. B-frags straight from L2-hot W2; x depth-2 prefetch.
__global__ __launch_bounds__(64) void qkv_proj(const float* __restrict__ x,
                                               const short* __restrict__ W2,
                                               short* __restrict__ Qb,
                                               short* __restrict__ Kb,
                                               short* __restrict__ Vt) {
    int lane = threadIdx.x;
    int l15 = lane & 15, quad = lane >> 4;
    int m0 = blockIdx.x * 16;
    int mrow = m0 + l15;

    f32x4 acc[12];
#pragma unroll
    for (int i = 0; i < 12; ++i) acc[i] = f32x4{0.f, 0.f, 0.f, 0.f};

    const float4* xp = (const float4*)x + (size_t)mrow * 256 + quad * 2;
    float4 xs[2][2];
    xs[0][0] = xp[0]; xs[0][1] = xp[1];
    xs[1][0] = xp[8]; xs[1][1] = xp[9];

    for (int kc = 0; kc < 32; ++kc) {
        float4 x0 = xs[kc & 1][0], x1 = xs[kc & 1][1];
        if (kc + 2 < 32) {
            xs[kc & 1][0] = xp[(kc + 2) * 8];
            xs[kc & 1][1] = xp[(kc + 2) * 8 + 1];
        }
        bf16x8 af;
        af[0] = f2bf(x0.x); af[1] = f2bf(x0.y); af[2] = f2bf(x0.z); af[3] = f2bf(x0.w);
        af[4] = f2bf(x1.x); af[5] = f2bf(x1.y); af[6] = f2bf(x1.z); af[7] = f2bf(x1.w);
        const short* wb = W2 + (size_t)(kc * 12) * 512 + lane * 8;
#pragma unroll
        for (int nt = 0; nt < 12; ++nt) {
            bf16x8 bf = *(const bf16x8*)(wb + nt * 512);
            acc[nt] = __builtin_amdgcn_mfma_f32_16x16x32_bf16(af, bf, acc[nt], 0, 0, 0);
        }
    }

    // epilogue: C layout col=l15, row=quad*4+r
    int b = blockIdx.x >> 7;                 // 16 rows per block, 2048 rows per batch
    int sbase = (m0 + quad * 4) & 2047;
#pragma unroll
    for (int nt = 0; nt < 12; ++nt) {
        if (nt < 8) {
            short* dst = (nt < 4) ? Kb : Qb;
            int h = (nt & 3) * 16 + l15;
#pragma unroll
            for (int r = 0; r < 4; ++r)
                dst[(size_t)(m0 + quad * 4 + r) * HD + h] = f2bf(acc[nt][r]);
        } else {
            int h = (nt - 8) * 16 + l15;
            short4 o;
            o.x = f2bf(acc[nt][0]); o.y = f2bf(acc[nt][1]);
            o.z = f2bf(acc[nt][2]); o.w = f2bf(acc[nt][3]);
            *(short4*)(Vt + ((size_t)(b * 64 + h)) * TB + sbase) = o;
        }
    }
}

// ---------- K3: causal flash, one independent wave per 16 queries ----------
#define PPAD 72
__global__ __launch_bounds__(64) void flash(const short* __restrict__ Qb,
                                            const short* __restrict__ Kb,
                                            const short* __restrict__ Vt,
                                            float* __restrict__ out) {
    __shared__ short Psh[16 * PPAD];
    int lane = threadIdx.x;
    int l15 = lane & 15, quad = lane >> 4;
    // causal-length balancing swizzle: CU-resident waves get complementary work
    int phase = blockIdx.x >> 8, idx = blockIdx.x & 255;
    int b = idx >> 5, j = idx & 31;
    int q = (phase == 0) ? 127 - j : (phase == 1) ? j : (phase == 2) ? 95 - j : 32 + j;
    int tq0 = q * 16;
    size_t bT = (size_t)b * TB;

    const short* qrow = Qb + (bT + tq0 + l15) * HD;
    bf16x8 qf0 = *(const bf16x8*)(qrow + quad * 8);
    bf16x8 qf1 = *(const bf16x8*)(qrow + 32 + quad * 8);

    f32x4 accO[4];
#pragma unroll
    for (int i = 0; i < 4; ++i) accO[i] = f32x4{0.f, 0.f, 0.f, 0.f};
    float mrow[4], lrow[4];
#pragma unroll
    for (int r = 0; r < 4; ++r) { mrow[r] = -1e30f; lrow[r] = 0.f; }

    int nk = tq0 + 16;
    int ntiles = (nk + 63) >> 6;
    const short* kbase = Kb + bT * HD;
    const short* vbase0 = Vt + bT * HD;      // Vt[b] = [64][2048]

    bf16x8 kf[8];
#pragma unroll
    for (int st = 0; st < 4; ++st) {
        const short* kr = kbase + (size_t)(st * 16 + l15) * HD + quad * 8;
        kf[st * 2]     = *(const bf16x8*)(kr);
        kf[st * 2 + 1] = *(const bf16x8*)(kr + 32);
    }

    for (int t = 0; t < ntiles; ++t) {
        int s0 = t * 64;
        // V^T frags for this tile (overlaps with QK/softmax)
        bf16x8 vf[8];
        const short* vb = vbase0 + s0 + quad * 8;
#pragma unroll
        for (int ht = 0; ht < 4; ++ht) {
            const short* vr = vb + (size_t)(ht * 16 + l15) * TB;
            vf[ht * 2]     = *(const bf16x8*)(vr);
            vf[ht * 2 + 1] = *(const bf16x8*)(vr + 32);
        }
        // S = Q K^T over 64 keys (4 n-subtiles x k=64)
        f32x4 sv[4];
#pragma unroll
        for (int st = 0; st < 4; ++st) {
            f32x4 s = f32x4{0.f, 0.f, 0.f, 0.f};
            s = __builtin_amdgcn_mfma_f32_16x16x32_bf16(qf0, kf[st * 2], s, 0, 0, 0);
            s = __builtin_amdgcn_mfma_f32_16x16x32_bf16(qf1, kf[st * 2 + 1], s, 0, 0, 0);
            sv[st] = s;
        }
        // prefetch next K tile while softmax runs
        if (t + 1 < ntiles) {
            const short* kb2 = kbase + (size_t)(s0 + 64) * HD + quad * 8;
#pragma unroll
            for (int st = 0; st < 4; ++st) {
                const short* kr = kb2 + (size_t)(st * 16) * HD + (size_t)l15 * HD;
                kf[st * 2]     = *(const bf16x8*)(kr);
                kf[st * 2 + 1] = *(const bf16x8*)(kr + 32);
            }
        }
        bool full = (s0 + 64 <= tq0);
#pragma unroll
        for (int r = 0; r < 4; ++r) {
            int tg = tq0 + quad * 4 + r;
            float v0, v1, v2, v3;
            if (full) {
                v0 = sv[0][r] * SCALE; v1 = sv[1][r] * SCALE;
                v2 = sv[2][r] * SCALE; v3 = sv[3][r] * SCALE;
            } else {
                int sg = s0 + l15;
                v0 = (sg      <= tg) ? sv[0][r] * SCALE : -1e30f;
                v1 = (sg + 16 <= tg) ? sv[1][r] * SCALE : -1e30f;
                v2 = (sg + 32 <= tg) ? sv[2][r] * SCALE : -1e30f;
                v3 = (sg + 48 <= tg) ? sv[3][r] * SCALE : -1e30f;
            }
            float mx = fmaxf(fmaxf(v0, v1), fmaxf(v2, v3));
            mx = fmaxf(mx, __shfl_xor(mx, 1));
            mx = fmaxf(mx, __shfl_xor(mx, 2));
            mx = fmaxf(mx, __shfl_xor(mx, 4));
            mx = fmaxf(mx, __shfl_xor(mx, 8));
            float mn = fmaxf(mrow[r], mx);
            float e0 = __expf(v0 - mn), e1 = __expf(v1 - mn);
            float e2 = __expf(v2 - mn), e3 = __expf(v3 - mn);
            float rs = (e0 + e1) + (e2 + e3);
            rs += __shfl_xor(rs, 1);
            rs += __shfl_xor(rs, 2);
            rs += __shfl_xor(rs, 4);
            rs += __shfl_xor(rs, 8);
            float alpha = __expf(mrow[r] - mn);
            lrow[r] = lrow[r] * alpha + rs;
            mrow[r] = mn;
#pragma unroll
            for (int ht = 0; ht < 4; ++ht) accO[ht][r] *= alpha;
            int prow = (quad * 4 + r) * PPAD;
            Psh[prow + l15]      = f2bf(e0);
            Psh[prow + 16 + l15] = f2bf(e1);
            Psh[prow + 32 + l15] = f2bf(e2);
            Psh[prow + 48 + l15] = f2bf(e3);
        }
        // wave-local LDS transpose: drain DS writes before cross-lane read
        asm volatile("s_waitcnt lgkmcnt(0)" ::: "memory");
        bf16x8 pf0 = *(const bf16x8*)&Psh[l15 * PPAD + quad * 8];
        bf16x8 pf1 = *(const bf16x8*)&Psh[l15 * PPAD + 32 + quad * 8];
#pragma unroll
        for (int ht = 0; ht < 4; ++ht) {
            accO[ht] = __builtin_amdgcn_mfma_f32_16x16x32_bf16(pf0, vf[ht * 2], accO[ht], 0, 0, 0);
            accO[ht] = __builtin_amdgcn_mfma_f32_16x16x32_bf16(pf1, vf[ht * 2 + 1], accO[ht], 0, 0, 0);
        }
    }

#pragma unroll
    for (int r = 0; r < 4; ++r) {
        float inv = 1.0f / lrow[r];
        int tg = tq0 + quad * 4 + r;
#pragma unroll
        for (int ht = 0; ht < 4; ++ht)
            out[(bT + tg) * HD + ht * 16 + l15] = accO[ht][r] * inv;
    }
}

extern "C" void kernel_launch(void* const* d_in, const int* in_sizes, int n_in,
                              void* d_out, int out_size, void* d_ws, size_t ws_size,
                              hipStream_t stream) {
    const float* x  = (const float*)d_in[0];
    const float* Wk = (const float*)d_in[1];
    const float* Wq = (const float*)d_in[2];
    const float* Wv = (const float*)d_in[3];
    float* out = (float*)d_out;

    short* W2 = (short*)d_ws;                // 192*1024 bf16 (frag-packed)
    short* Qb = W2 + 192 * 1024;
    short* Kb = Qb + (size_t)BT * HD;
    short* Vt = Kb + (size_t)BT * HD;        // [B][64][2048] transposed V

    wpack<<<96, 256, 0, stream>>>(Wk, Wq, Wv, W2);
    qkv_proj<<<BT / 16, 64, 0, stream>>>(x, W2, Qb, Kb, Vt);
    flash<<<NB * (TB / 16), 64, 0, stream>>>(Qb, Kb, Vt, out);
}

// Round 3
// 220.562 us; speedup vs baseline: 1.1473x; 1.1473x over previous
//
#include <hip/hip_runtime.h>

// Problem constants (B=8, T=2048, C=1024, H=64)
#define TB 2048
#define NB 8
#define CEMB 1024
#define HD 64
#define BT (NB*TB)
#define SCALE 0.03125f   // 1/sqrt(1024) — reference scales by n_embd

typedef __attribute__((ext_vector_type(8))) short bf16x8;
typedef __attribute__((ext_vector_type(4))) float f32x4;

__device__ inline short f2bf(float f) {
    union { float f; unsigned u; } v; v.f = f;
    unsigned r = v.u + 0x7fffu + ((v.u >> 16) & 1u);   // RNE
    return (short)(r >> 16);
}

// ---------- K1: pack [Wk;Wq;Wv] into MFMA B-frag order, bf16 ----------
// chunk c: lane=c&63, ntk=c>>6, nt=ntk%12, kc=ntk/12 (kc = 32-col chunk)
// W2[c*8+j] = W[n=nt*16+(lane&15)][kc*32+(lane>>4)*8+j]
__global__ __launch_bounds__(256) void wpack(const float* __restrict__ Wk,
                                             const float* __restrict__ Wq,
                                             const float* __restrict__ Wv,
                                             short* __restrict__ W2) {
    int c = blockIdx.x * 256 + threadIdx.x;          // 96 blocks
    int lane = c & 63, ntk = c >> 6;
    int nt = ntk % 12, kc = ntk / 12;
    int n = nt * 16 + (lane & 15);
    int col = kc * 32 + (lane >> 4) * 8;
    const float* src = (n < 64) ? Wk + n * 1024
                     : (n < 128) ? Wq + (n - 64) * 1024
                                 : Wv + (n - 128) * 1024;
    float4 a = *(const float4*)(src + col);
    float4 b = *(const float4*)(src + col + 4);
    bf16x8 o;
    o[0] = f2bf(a.x); o[1] = f2bf(a.y); o[2] = f2bf(a.z); o[3] = f2bf(a.w);
    o[4] = f2bf(b.x); o[5] = f2bf(b.y); o[6] = f2bf(b.z); o[7] = f2bf(b.w);
    *(bf16x8*)(W2 + (size_t)c * 8) = o;
}

// ---------- K2: QKV projection, K-split x4 across waves ----------
// Block = 16 rows; wave w covers cols [w*256,(w+1)*256). One barrier total.
__global__ __launch_bounds__(256, 3) void qkv_proj(const float* __restrict__ x,
                                                   const short* __restrict__ W2,
                                                   short* __restrict__ Qb,
                                                   short* __restrict__ Kb,
                                                   short* __restrict__ Vt) {
    __shared__ f32x4 Lred[4][3][3][64];   // [owner][writer_rank][nt_local][lane] = 36 KB
    int tid = threadIdx.x, wave = tid >> 6, lane = tid & 63;
    int l15 = lane & 15, quad = lane >> 4;
    int m0 = blockIdx.x * 16;
    int mrow = m0 + l15;

    f32x4 acc[12];
#pragma unroll
    for (int i = 0; i < 12; ++i) acc[i] = f32x4{0.f, 0.f, 0.f, 0.f};

    const float* xb = x + (size_t)mrow * CEMB + wave * 256 + quad * 8;
    float4 pa0 = *(const float4*)(xb);
    float4 pa1 = *(const float4*)(xb + 4);
    float4 pb0 = *(const float4*)(xb + 32);
    float4 pb1 = *(const float4*)(xb + 36);

#pragma unroll
    for (int kc = 0; kc < 8; ++kc) {
        float4 x0 = (kc & 1) ? pb0 : pa0;
        float4 x1 = (kc & 1) ? pb1 : pa1;
        if (kc + 2 < 8) {
            const float4* nx = (const float4*)(xb + (kc + 2) * 32);
            if (kc & 1) { pb0 = nx[0]; pb1 = nx[1]; }
            else        { pa0 = nx[0]; pa1 = nx[1]; }
        }
        bf16x8 af;
        af[0] = f2bf(x0.x); af[1] = f2bf(x0.y); af[2] = f2bf(x0.z); af[3] = f2bf(x0.w);
        af[4] = f2bf(x1.x); af[5] = f2bf(x1.y); af[6] = f2bf(x1.z); af[7] = f2bf(x1.w);
        const short* wb = W2 + ((size_t)((wave * 8 + kc) * 12) * 64 + lane) * 8;
#pragma unroll
        for (int nt = 0; nt < 12; ++nt) {
            bf16x8 bf = *(const bf16x8*)(wb + nt * 512);
            acc[nt] = __builtin_amdgcn_mfma_f32_16x16x32_bf16(af, bf, acc[nt], 0, 0, 0);
        }
    }

    // exchange partials (each wave owns nt = 3*wave + {0,1,2})
#pragma unroll
    for (int nt = 0; nt < 12; ++nt) {
        int o = nt / 3;
        if (o != wave) {
            int rank = wave - (wave > o ? 1 : 0);
            Lred[o][rank][nt % 3][lane] = acc[nt];
        }
    }
    __syncthreads();

    int b = blockIdx.x >> 7;
    int sbase = (m0 & 2047) + quad * 4;
#pragma unroll
    for (int ntl = 0; ntl < 3; ++ntl) {
        int nt = wave * 3 + ntl;
        f32x4 s = acc[nt];
#pragma unroll
        for (int rk = 0; rk < 3; ++rk) s += Lred[wave][rk][ntl][lane];
        if (nt < 8) {
            short* dst = (nt < 4) ? Kb : Qb;
            int h = (nt & 3) * 16 + l15;
#pragma unroll
            for (int r = 0; r < 4; ++r)
                dst[(size_t)(m0 + quad * 4 + r) * HD + h] = f2bf(s[r]);
        } else {
            int h = (nt - 8) * 16 + l15;
            short4 o4;
            o4.x = f2bf(s[0]); o4.y = f2bf(s[1]); o4.z = f2bf(s[2]); o4.w = f2bf(s[3]);
            *(short4*)(Vt + ((size_t)(b * 64 + h)) * TB + sbase) = o4;
        }
    }
}

// ---------- K3: causal flash, key-range split x4 across waves ----------
#define PPAD 72
__global__ __launch_bounds__(256, 3) void flash(const short* __restrict__ Qb,
                                                const short* __restrict__ Kb,
                                                const short* __restrict__ Vt,
                                                float* __restrict__ out) {
    __shared__ short Psh[4][16 * PPAD];   // per-wave P relayout
    __shared__ float Of[4][16][68];       // per-wave un-normalized O (+pad)
    __shared__ float Ml[4][2][16];        // per-wave m,l per row
    int tid = threadIdx.x, wave = tid >> 6, lane = tid & 63;
    int l15 = lane & 15, quad = lane >> 4;
    // block -> (b, q); each CU's 4 consecutive blocks have constant total work
    int i = blockIdx.x, b = i >> 7, r7 = i & 127, g = r7 >> 2, sel = r7 & 3;
    int q = (sel == 0) ? g : (sel == 1) ? 63 - g : (sel == 2) ? 64 + g : 127 - g;
    int tq0 = q * 16;
    size_t bT = (size_t)b * TB;

    const short* qrow = Qb + (bT + tq0 + l15) * HD;
    bf16x8 qf0 = *(const bf16x8*)(qrow + quad * 8);
    bf16x8 qf1 = *(const bf16x8*)(qrow + 32 + quad * 8);

    f32x4 accO[4];
#pragma unroll
    for (int k = 0; k < 4; ++k) accO[k] = f32x4{0.f, 0.f, 0.f, 0.f};
    float mrow[4], lrow[4];
#pragma unroll
    for (int r = 0; r < 4; ++r) { mrow[r] = -1e30f; lrow[r] = 0.f; }

    int ntiles = (q + 4) >> 2;            // ceil((q*16+16)/64)
    const short* kbase = Kb + bT * HD;
    const short* vbase = Vt + bT * HD;    // [64][2048]

    int myt = wave;
    if (myt < ntiles) {
        bf16x8 kf[8];
        {
            const short* kr = kbase + (size_t)(myt * 64 + l15) * HD + quad * 8;
#pragma unroll
            for (int st = 0; st < 4; ++st) {
                kf[st * 2]     = *(const bf16x8*)(kr + (size_t)st * 16 * HD);
                kf[st * 2 + 1] = *(const bf16x8*)(kr + (size_t)st * 16 * HD + 32);
            }
        }
        for (; myt < ntiles; myt += 4) {
            int s0 = myt * 64;
            bf16x8 vf[8];
            const short* vb = vbase + s0 + quad * 8;
#pragma unroll
            for (int ht = 0; ht < 4; ++ht) {
                const short* vr = vb + (size_t)(ht * 16 + l15) * TB;
                vf[ht * 2]     = *(const bf16x8*)(vr);
                vf[ht * 2 + 1] = *(const bf16x8*)(vr + 32);
            }
            f32x4 sv[4];
#pragma unroll
            for (int st = 0; st < 4; ++st) {
                f32x4 s = f32x4{0.f, 0.f, 0.f, 0.f};
                s = __builtin_amdgcn_mfma_f32_16x16x32_bf16(qf0, kf[st * 2], s, 0, 0, 0);
                s = __builtin_amdgcn_mfma_f32_16x16x32_bf16(qf1, kf[st * 2 + 1], s, 0, 0, 0);
                sv[st] = s;
            }
            if (myt + 4 < ntiles) {
                const short* kr = kbase + (size_t)(s0 + 256 + l15) * HD + quad * 8;
#pragma unroll
                for (int st = 0; st < 4; ++st) {
                    kf[st * 2]     = *(const bf16x8*)(kr + (size_t)st * 16 * HD);
                    kf[st * 2 + 1] = *(const bf16x8*)(kr + (size_t)st * 16 * HD + 32);
                }
            }
            bool full = (s0 + 64 <= tq0);
#pragma unroll
            for (int r = 0; r < 4; ++r) {
                int tg = tq0 + quad * 4 + r;
                float v0, v1, v2, v3;
                if (full) {
                    v0 = sv[0][r] * SCALE; v1 = sv[1][r] * SCALE;
                    v2 = sv[2][r] * SCALE; v3 = sv[3][r] * SCALE;
                } else {
                    int sg = s0 + l15;
                    v0 = (sg      <= tg) ? sv[0][r] * SCALE : -1e30f;
                    v1 = (sg + 16 <= tg) ? sv[1][r] * SCALE : -1e30f;
                    v2 = (sg + 32 <= tg) ? sv[2][r] * SCALE : -1e30f;
                    v3 = (sg + 48 <= tg) ? sv[3][r] * SCALE : -1e30f;
                }
                float mx = fmaxf(fmaxf(v0, v1), fmaxf(v2, v3));
                mx = fmaxf(mx, __shfl_xor(mx, 1));
                mx = fmaxf(mx, __shfl_xor(mx, 2));
                mx = fmaxf(mx, __shfl_xor(mx, 4));
                mx = fmaxf(mx, __shfl_xor(mx, 8));
                float mn = fmaxf(mrow[r], mx);
                float e0 = __expf(v0 - mn), e1 = __expf(v1 - mn);
                float e2 = __expf(v2 - mn), e3 = __expf(v3 - mn);
                float rs = (e0 + e1) + (e2 + e3);
                rs += __shfl_xor(rs, 1);
                rs += __shfl_xor(rs, 2);
                rs += __shfl_xor(rs, 4);
                rs += __shfl_xor(rs, 8);
                float alpha = __expf(mrow[r] - mn);
                lrow[r] = lrow[r] * alpha + rs;
                mrow[r] = mn;
#pragma unroll
                for (int ht = 0; ht < 4; ++ht) accO[ht][r] *= alpha;
                int prow = (quad * 4 + r) * PPAD;
                Psh[wave][prow + l15]      = f2bf(e0);
                Psh[wave][prow + 16 + l15] = f2bf(e1);
                Psh[wave][prow + 32 + l15] = f2bf(e2);
                Psh[wave][prow + 48 + l15] = f2bf(e3);
            }
            asm volatile("s_waitcnt lgkmcnt(0)" ::: "memory");
            bf16x8 pf0 = *(const bf16x8*)&Psh[wave][l15 * PPAD + quad * 8];
            bf16x8 pf1 = *(const bf16x8*)&Psh[wave][l15 * PPAD + 32 + quad * 8];
#pragma unroll
            for (int ht = 0; ht < 4; ++ht) {
                accO[ht] = __builtin_amdgcn_mfma_f32_16x16x32_bf16(pf0, vf[ht * 2], accO[ht], 0, 0, 0);
                accO[ht] = __builtin_amdgcn_mfma_f32_16x16x32_bf16(pf1, vf[ht * 2 + 1], accO[ht], 0, 0, 0);
            }
        }
    }

    // ---- merge 4 partial flash states ----
#pragma unroll
    for (int ht = 0; ht < 4; ++ht)
#pragma unroll
        for (int r = 0; r < 4; ++r)
            Of[wave][quad * 4 + r][ht * 16 + l15] = accO[ht][r];
    if (l15 == 0) {
#pragma unroll
        for (int r = 0; r < 4; ++r) {
            Ml[wave][0][quad * 4 + r] = mrow[r];
            Ml[wave][1][quad * 4 + r] = lrow[r];
        }
    }
    __syncthreads();

    int row = tid >> 4, c4 = (tid & 15) * 4;
    float m0 = Ml[0][0][row], m1 = Ml[1][0][row];
    float m2 = Ml[2][0][row], m3 = Ml[3][0][row];
    float M = fmaxf(fmaxf(m0, m1), fmaxf(m2, m3));
    float e0 = __expf(m0 - M), e1 = __expf(m1 - M);
    float e2 = __expf(m2 - M), e3 = __expf(m3 - M);
    float L = Ml[0][1][row] * e0 + Ml[1][1][row] * e1
            + Ml[2][1][row] * e2 + Ml[3][1][row] * e3;
    float inv = 1.0f / L;
    float4 o;
    o.x = (Of[0][row][c4+0]*e0 + Of[1][row][c4+0]*e1 + Of[2][row][c4+0]*e2 + Of[3][row][c4+0]*e3) * inv;
    o.y = (Of[0][row][c4+1]*e0 + Of[1][row][c4+1]*e1 + Of[2][row][c4+1]*e2 + Of[3][row][c4+1]*e3) * inv;
    o.z = (Of[0][row][c4+2]*e0 + Of[1][row][c4+2]*e1 + Of[2][row][c4+2]*e2 + Of[3][row][c4+2]*e3) * inv;
    o.w = (Of[0][row][c4+3]*e0 + Of[1][row][c4+3]*e1 + Of[2][row][c4+3]*e2 + Of[3][row][c4+3]*e3) * inv;
    *(float4*)(out + (bT + tq0 + row) * HD + c4) = o;
}

extern "C" void kernel_launch(void* const* d_in, const int* in_sizes, int n_in,
                              void* d_out, int out_size, void* d_ws, size_t ws_size,
                              hipStream_t stream) {
    const float* x  = (const float*)d_in[0];
    const float* Wk = (const float*)d_in[1];
    const float* Wq = (const float*)d_in[2];
    const float* Wv = (const float*)d_in[3];
    float* out = (float*)d_out;

    short* W2 = (short*)d_ws;                // 192*1024 bf16 (frag-packed)
    short* Qb = W2 + 192 * 1024;
    short* Kb = Qb + (size_t)BT * HD;
    short* Vt = Kb + (size_t)BT * HD;        // [B][64][2048] transposed V

    wpack<<<96, 256, 0, stream>>>(Wk, Wq, Wv, W2);
    qkv_proj<<<1024, 256, 0, stream>>>(x, W2, Qb, Kb, Vt);
    flash<<<1024, 256, 0, stream>>>(Qb, Kb, Vt, out);
}